// Round 2
// baseline (316.718 us; speedup 1.0000x reference)
//
#include <hip/hip_runtime.h>

// ============================================================================
// Compile-time real-basis Wigner 3j — mirrors the reference _su2_cg/_q/_w3j
// exactly (double precision at compile time, cast to float for use).
// ============================================================================

__host__ __device__ constexpr double cfact(int n) {
    double r = 1.0;
    for (int i = 2; i <= n; ++i) r *= (double)i;
    return r;
}

__host__ __device__ constexpr double csqrt(double x) {
    if (x <= 0.0) return 0.0;
    double r = x < 1.0 ? 1.0 : x;
    for (int i = 0; i < 80; ++i) r = 0.5 * (r + x / r);
    return r;
}

__host__ __device__ constexpr double su2_cg_elem(int j1, int j2, int j3, int m1, int m2) {
    int m3 = m1 + m2;
    if (m3 < -j3 || m3 > j3) return 0.0;
    double pref = csqrt((double)(2 * j3 + 1) * cfact(j3 + j1 - j2) * cfact(j3 - j1 + j2) *
                        cfact(j1 + j2 - j3) / cfact(j1 + j2 + j3 + 1));
    pref *= csqrt(cfact(j3 + m3) * cfact(j3 - m3) * cfact(j1 - m1) * cfact(j1 + m1) *
                  cfact(j2 - m2) * cfact(j2 + m2));
    double s = 0.0;
    for (int k = 0; k <= j1 + j2 - j3; ++k) {
        int t0 = k, t1 = j1 + j2 - j3 - k, t2 = j1 - m1 - k;
        int t3 = j2 + m2 - k, t4 = j3 - j2 + m1 + k, t5 = j3 - j1 - m2 + k;
        if (t0 < 0 || t1 < 0 || t2 < 0 || t3 < 0 || t4 < 0 || t5 < 0) continue;
        double term = 1.0 / (cfact(t0) * cfact(t1) * cfact(t2) * cfact(t3) * cfact(t4) * cfact(t5));
        s += (k & 1) ? -term : term;
    }
    return pref * s;
}

struct QM { double re[5][5]; double im[5][5]; };

__host__ __device__ constexpr QM qmat(int l) {
    QM q{};
    const double inv2 = 1.0 / csqrt(2.0);
    for (int m = -l; m < 0; ++m) {
        q.re[l + m][l - m] = inv2;
        q.im[l + m][l + m] = -inv2;
    }
    q.re[l][l] = 1.0;
    for (int m = 1; m <= l; ++m) {
        double s = (m & 1) ? -1.0 : 1.0;
        q.re[l + m][l + m] = s * inv2;
        q.im[l + m][l - m] = s * inv2;
    }
    double pr = 1.0, pi = 0.0;
    switch (l & 3) {
        case 1: pr = 0.0; pi = -1.0; break;
        case 2: pr = -1.0; pi = 0.0; break;
        case 3: pr = 0.0; pi = 1.0; break;
        default: break;
    }
    for (int a = 0; a < 5; ++a)
        for (int b = 0; b < 5; ++b) {
            double re = q.re[a][b], im = q.im[a][b];
            q.re[a][b] = re * pr - im * pi;
            q.im[a][b] = re * pi + im * pr;
        }
    return q;
}

struct W3 { double w[5][5][5]; };

__host__ __device__ constexpr W3 make_w3j(int l1, int l2, int l3) {
    W3 o{};
    const int n1 = 2 * l1 + 1, n2 = 2 * l2 + 1, n3 = 2 * l3 + 1;
    double C[5][5]{};
    const double inv = 1.0 / csqrt((double)(2 * l3 + 1));
    for (int i = 0; i < n1; ++i)
        for (int k = 0; k < n2; ++k)
            C[i][k] = su2_cg_elem(l1, l2, l3, i - l1, k - l2) * inv;
    const QM q1 = qmat(l1), q2 = qmat(l2), q3 = qmat(l3);
    for (int j = 0; j < n1; ++j)
        for (int l = 0; l < n2; ++l)
            for (int n = 0; n < n3; ++n) {
                double s = 0.0;
                for (int i = 0; i < n1; ++i)
                    for (int k = 0; k < n2; ++k) {
                        int m = (i - l1) + (k - l2) + l3;
                        if (m < 0 || m >= n3) continue;
                        double cg = C[i][k];
                        if (cg == 0.0) continue;
                        double r1 = q1.re[i][j], i1 = q1.im[i][j];
                        double r2 = q2.re[k][l], i2 = q2.im[k][l];
                        double zr = r1 * r2 - i1 * i2, zi = r1 * i2 + i1 * r2;
                        s += cg * (zr * q3.re[m][n] + zi * q3.im[m][n]);
                    }
                o.w[j][l][n] = s;
            }
    return o;
}

template <int L1, int L2, int L3>
__device__ __forceinline__ void tp_path(float wk, const float* a, const float* b, float* o) {
    constexpr W3 W = make_w3j(L1, L2, L3);
    constexpr double AL = csqrt(2.0 * L3 + 1.0);
#pragma unroll
    for (int n = 0; n < 2 * L3 + 1; ++n) {
        float s = 0.0f;
#pragma unroll
        for (int i = 0; i < 2 * L1 + 1; ++i) {
#pragma unroll
            for (int k = 0; k < 2 * L2 + 1; ++k) {
                const double cw = W.w[i][k][n] * AL;
                if (cw != 0.0) s += (float)cw * (a[i] * b[k]);
            }
        }
        o[n] = wk * s;
    }
}

// ---- vector types with 4-byte alignment (addresses are only dword-aligned) ----
typedef float f2v __attribute__((ext_vector_type(2)));
typedef float f4v __attribute__((ext_vector_type(4)));
typedef f2v f2u __attribute__((aligned(4)));
typedef f4v f4u __attribute__((aligned(4)));

// nontemporal streaming helpers
__device__ __forceinline__ float ntl1(const float* p) { return __builtin_nontemporal_load(p); }
__device__ __forceinline__ f2v ntl2(const float* p) { return __builtin_nontemporal_load((const f2u*)p); }
__device__ __forceinline__ f4v ntl4(const float* p) { return __builtin_nontemporal_load((const f4u*)p); }
__device__ __forceinline__ void nts1(float v, float* p) { __builtin_nontemporal_store(v, p); }
__device__ __forceinline__ void nts2(f2v v, float* p) { __builtin_nontemporal_store(v, (f2u*)p); }
__device__ __forceinline__ void nts4(f4v v, float* p) { __builtin_nontemporal_store(v, (f4u*)p); }

__device__ __forceinline__ void store3(const float* t, float* p) {
    nts2(f2v{t[0], t[1]}, p);
    nts1(t[2], p + 2);
}
__device__ __forceinline__ void store5(const float* t, float* p) {
    nts4(f4v{t[0], t[1], t[2], t[3]}, p);
    nts1(t[4], p + 4);
}

// ============================================================================
// Kernel: one thread per (edge, u-channel). wave = one edge, lane = u (0..63).
// ============================================================================

__global__ __launch_bounds__(256) void dtp_kernel(const float* __restrict__ X1,
                                                  const float* __restrict__ X2,
                                                  const float* __restrict__ WT,
                                                  float* __restrict__ OUT, int E) {
    long idx = (long)blockIdx.x * blockDim.x + threadIdx.x;
    if (idx >= (long)E * 64) return;
    long e = idx >> 6;
    int u = (int)(idx & 63);

    const float* p1 = X1 + e * 576;
    const float* p2 = X2 + e * 9;
    const float* pw = WT + e * 960;
    float* po = OUT + e * 3264;

    // ---- x1 loads (nontemporal, vectorized) ----
    float a0 = ntl1(p1 + u);
    float a1[3], a2[5];
    {
        f2v v = ntl2(p1 + 64 + u * 3);
        a1[0] = v.x; a1[1] = v.y;
        a1[2] = ntl1(p1 + 64 + u * 3 + 2);
        f4v w4 = ntl4(p1 + 256 + u * 5);
        a2[0] = w4.x; a2[1] = w4.y; a2[2] = w4.z; a2[3] = w4.w;
        a2[4] = ntl1(p1 + 256 + u * 5 + 4);
    }

    // ---- x2 loads (tiny, wave-uniform, keep cached) ----
    float b0 = p2[0];
    float b1[3], b2[5];
#pragma unroll
    for (int m = 0; m < 3; ++m) b1[m] = p2[1 + m];
#pragma unroll
    for (int m = 0; m < 5; ++m) b2[m] = p2[4 + m];

    // ---- weights (nontemporal, coalesced stride-64) ----
    float wk[15];
#pragma unroll
    for (int k = 0; k < 15; ++k) wk[k] = ntl1(pw + k * 64 + u);

    float A0[1] = {a0}, B0[1] = {b0};
    float t1[1], t3[3], t5[5];

    // ---- l3 = 0 outputs ----
    tp_path<0, 0, 0>(wk[0], A0, B0, t1);  nts1(t1[0], po + 0 + u);
    tp_path<1, 1, 0>(wk[1], a1, b1, t1);  nts1(t1[0], po + 64 + u);
    tp_path<2, 2, 0>(wk[2], a2, b2, t1);  nts1(t1[0], po + 128 + u);

    // ---- l3 = 1 outputs ----
    tp_path<0, 1, 1>(wk[3], A0, b1, t3);  store3(t3, po + 192 + u * 3);
    tp_path<1, 0, 1>(wk[4], a1, B0, t3);  store3(t3, po + 384 + u * 3);
    tp_path<1, 2, 1>(wk[5], a1, b2, t3);  store3(t3, po + 576 + u * 3);
    tp_path<2, 1, 1>(wk[6], a2, b1, t3);  store3(t3, po + 768 + u * 3);
    tp_path<1, 1, 1>(wk[7], a1, b1, t3);  store3(t3, po + 960 + u * 3);
    tp_path<2, 2, 1>(wk[8], a2, b2, t3);  store3(t3, po + 1152 + u * 3);

    // ---- l3 = 2 outputs ----
    tp_path<0, 2, 2>(wk[9], A0, b2, t5);   store5(t5, po + 1344 + u * 5);
    tp_path<1, 1, 2>(wk[10], a1, b1, t5);  store5(t5, po + 1664 + u * 5);
    tp_path<2, 0, 2>(wk[11], a2, B0, t5);  store5(t5, po + 1984 + u * 5);
    tp_path<2, 2, 2>(wk[12], a2, b2, t5);  store5(t5, po + 2304 + u * 5);
    tp_path<1, 2, 2>(wk[13], a1, b2, t5);  store5(t5, po + 2624 + u * 5);
    tp_path<2, 1, 2>(wk[14], a2, b1, t5);  store5(t5, po + 2944 + u * 5);
}

extern "C" void kernel_launch(void* const* d_in, const int* in_sizes, int n_in,
                              void* d_out, int out_size, void* d_ws, size_t ws_size,
                              hipStream_t stream) {
    (void)n_in; (void)out_size; (void)d_ws; (void)ws_size;
    const float* x1 = (const float*)d_in[0];
    const float* x2 = (const float*)d_in[1];
    const float* wt = (const float*)d_in[2];
    float* out = (float*)d_out;

    int E = in_sizes[0] / 576;
    long total = (long)E * 64;
    int blocks = (int)((total + 255) / 256);
    dtp_kernel<<<blocks, 256, 0, stream>>>(x1, x2, wt, out, E);
}

// Round 4
// 188.035 us; speedup vs baseline: 1.6844x; 1.6844x over previous
//
#include <hip/hip_runtime.h>

// ============================================================================
// Compile-time real-basis Wigner 3j — mirrors the reference _su2_cg/_q/_w3j
// exactly (double precision at compile time, cast to float for use).
// ============================================================================

__host__ __device__ constexpr double cfact(int n) {
    double r = 1.0;
    for (int i = 2; i <= n; ++i) r *= (double)i;
    return r;
}

__host__ __device__ constexpr double csqrt(double x) {
    if (x <= 0.0) return 0.0;
    double r = x < 1.0 ? 1.0 : x;
    for (int i = 0; i < 80; ++i) r = 0.5 * (r + x / r);
    return r;
}

__host__ __device__ constexpr double su2_cg_elem(int j1, int j2, int j3, int m1, int m2) {
    int m3 = m1 + m2;
    if (m3 < -j3 || m3 > j3) return 0.0;
    double pref = csqrt((double)(2 * j3 + 1) * cfact(j3 + j1 - j2) * cfact(j3 - j1 + j2) *
                        cfact(j1 + j2 - j3) / cfact(j1 + j2 + j3 + 1));
    pref *= csqrt(cfact(j3 + m3) * cfact(j3 - m3) * cfact(j1 - m1) * cfact(j1 + m1) *
                  cfact(j2 - m2) * cfact(j2 + m2));
    double s = 0.0;
    for (int k = 0; k <= j1 + j2 - j3; ++k) {
        int t0 = k, t1 = j1 + j2 - j3 - k, t2 = j1 - m1 - k;
        int t3 = j2 + m2 - k, t4 = j3 - j2 + m1 + k, t5 = j3 - j1 - m2 + k;
        if (t0 < 0 || t1 < 0 || t2 < 0 || t3 < 0 || t4 < 0 || t5 < 0) continue;
        double term = 1.0 / (cfact(t0) * cfact(t1) * cfact(t2) * cfact(t3) * cfact(t4) * cfact(t5));
        s += (k & 1) ? -term : term;
    }
    return pref * s;
}

struct QM { double re[5][5]; double im[5][5]; };

__host__ __device__ constexpr QM qmat(int l) {
    QM q{};
    const double inv2 = 1.0 / csqrt(2.0);
    for (int m = -l; m < 0; ++m) {
        q.re[l + m][l - m] = inv2;
        q.im[l + m][l + m] = -inv2;
    }
    q.re[l][l] = 1.0;
    for (int m = 1; m <= l; ++m) {
        double s = (m & 1) ? -1.0 : 1.0;
        q.re[l + m][l + m] = s * inv2;
        q.im[l + m][l - m] = s * inv2;
    }
    double pr = 1.0, pi = 0.0;
    switch (l & 3) {
        case 1: pr = 0.0; pi = -1.0; break;
        case 2: pr = -1.0; pi = 0.0; break;
        case 3: pr = 0.0; pi = 1.0; break;
        default: break;
    }
    for (int a = 0; a < 5; ++a)
        for (int b = 0; b < 5; ++b) {
            double re = q.re[a][b], im = q.im[a][b];
            q.re[a][b] = re * pr - im * pi;
            q.im[a][b] = re * pi + im * pr;
        }
    return q;
}

struct W3 { double w[5][5][5]; };

__host__ __device__ constexpr W3 make_w3j(int l1, int l2, int l3) {
    W3 o{};
    const int n1 = 2 * l1 + 1, n2 = 2 * l2 + 1, n3 = 2 * l3 + 1;
    double C[5][5]{};
    const double inv = 1.0 / csqrt((double)(2 * l3 + 1));
    for (int i = 0; i < n1; ++i)
        for (int k = 0; k < n2; ++k)
            C[i][k] = su2_cg_elem(l1, l2, l3, i - l1, k - l2) * inv;
    const QM q1 = qmat(l1), q2 = qmat(l2), q3 = qmat(l3);
    for (int j = 0; j < n1; ++j)
        for (int l = 0; l < n2; ++l)
            for (int n = 0; n < n3; ++n) {
                double s = 0.0;
                for (int i = 0; i < n1; ++i)
                    for (int k = 0; k < n2; ++k) {
                        int m = (i - l1) + (k - l2) + l3;
                        if (m < 0 || m >= n3) continue;
                        double cg = C[i][k];
                        if (cg == 0.0) continue;
                        double r1 = q1.re[i][j], i1 = q1.im[i][j];
                        double r2 = q2.re[k][l], i2 = q2.im[k][l];
                        double zr = r1 * r2 - i1 * i2, zi = r1 * i2 + i1 * r2;
                        s += cg * (zr * q3.re[m][n] + zi * q3.im[m][n]);
                    }
                o.w[j][l][n] = s;
            }
    return o;
}

template <int L1, int L2, int L3>
__device__ __forceinline__ void tp_path(float wk, const float* a, const float* b, float* o) {
    constexpr W3 W = make_w3j(L1, L2, L3);
    constexpr double AL = csqrt(2.0 * L3 + 1.0);
#pragma unroll
    for (int n = 0; n < 2 * L3 + 1; ++n) {
        float s = 0.0f;
#pragma unroll
        for (int i = 0; i < 2 * L1 + 1; ++i) {
#pragma unroll
            for (int k = 0; k < 2 * L2 + 1; ++k) {
                const double cw = W.w[i][k][n] * AL;
                if (cw != 0.0) s += (float)cw * (a[i] * b[k]);
            }
        }
        o[n] = wk * s;
    }
}

// may_alias vector types: LDS is written as float and read as vectors — TBAA
// must not be allowed to reorder those accesses (R3 failure mode).
typedef float f4b __attribute__((ext_vector_type(4)));
typedef float f2b __attribute__((ext_vector_type(2)));
typedef f4b __attribute__((may_alias)) f4v;
typedef f2b __attribute__((may_alias)) f2v;

// ============================================================================
// Kernel: one thread per (edge, u-channel). wave = one edge, lane = u (0..63).
// Output staging: per-wave LDS buffer so every global store instruction is a
// fully-coalesced dwordx4 covering complete cache lines. __syncthreads()
// between LDS write and readback phases — full compiler memory fence + HW
// barrier (R3 relied on same-wave DS ordering; compiler reordered the reads).
// NOTE: grid is exact (E*64 % 256 == 0 for E=50000), so control flow at the
// barriers is uniform; the OOB guard is never taken.
// ============================================================================

__global__ __launch_bounds__(256) void dtp_kernel(const float* __restrict__ X1,
                                                  const float* __restrict__ X2,
                                                  const float* __restrict__ WT,
                                                  float* __restrict__ OUT, int E) {
    __shared__ __align__(16) float lds[4][1920];   // 7680 B per wave, 30 KiB/block

    long idx = (long)blockIdx.x * blockDim.x + threadIdx.x;
    if (idx >= (long)E * 64) return;
    long e = idx >> 6;
    int u = (int)(idx & 63);
    float* lbuf = lds[(threadIdx.x >> 6) & 3];

    const float* p1 = X1 + e * 576;
    const float* p2 = X2 + e * 9;
    const float* pw = WT + e * 960;
    float* po = OUT + e * 3264;

    // ---- x1 loads ----
    float a0 = p1[u];
    float a1[3], a2[5];
#pragma unroll
    for (int m = 0; m < 3; ++m) a1[m] = p1[64 + u * 3 + m];
#pragma unroll
    for (int m = 0; m < 5; ++m) a2[m] = p1[256 + u * 5 + m];

    // ---- x2 loads (tiny, wave-uniform) ----
    float b0 = p2[0];
    float b1[3], b2[5];
#pragma unroll
    for (int m = 0; m < 3; ++m) b1[m] = p2[1 + m];
#pragma unroll
    for (int m = 0; m < 5; ++m) b2[m] = p2[4 + m];

    // ---- weights (coalesced stride-64) ----
    float wk[15];
#pragma unroll
    for (int k = 0; k < 15; ++k) wk[k] = pw[k * 64 + u];

    float A0[1] = {a0}, B0[1] = {b0};
    float t1[1], t3[3], t5[5];

    // ---- l3 = 0 outputs: direct, already full-line coalesced ----
    tp_path<0, 0, 0>(wk[0], A0, B0, t1);  po[0 + u] = t1[0];
    tp_path<1, 1, 0>(wk[1], a1, b1, t1);  po[64 + u] = t1[0];
    tp_path<2, 2, 0>(wk[2], a2, b2, t1);  po[128 + u] = t1[0];

    // ---- l3 = 1 outputs: 6 paths -> lbuf[0..1152) == po[192..1344) ----
    tp_path<0, 1, 1>(wk[3], A0, b1, t3);
#pragma unroll
    for (int m = 0; m < 3; ++m) lbuf[0 * 192 + u * 3 + m] = t3[m];
    tp_path<1, 0, 1>(wk[4], a1, B0, t3);
#pragma unroll
    for (int m = 0; m < 3; ++m) lbuf[1 * 192 + u * 3 + m] = t3[m];
    tp_path<1, 2, 1>(wk[5], a1, b2, t3);
#pragma unroll
    for (int m = 0; m < 3; ++m) lbuf[2 * 192 + u * 3 + m] = t3[m];
    tp_path<2, 1, 1>(wk[6], a2, b1, t3);
#pragma unroll
    for (int m = 0; m < 3; ++m) lbuf[3 * 192 + u * 3 + m] = t3[m];
    tp_path<1, 1, 1>(wk[7], a1, b1, t3);
#pragma unroll
    for (int m = 0; m < 3; ++m) lbuf[4 * 192 + u * 3 + m] = t3[m];
    tp_path<2, 2, 1>(wk[8], a2, b2, t3);
#pragma unroll
    for (int m = 0; m < 3; ++m) lbuf[5 * 192 + u * 3 + m] = t3[m];

    __syncthreads();   // writes visible before readback

    // flush: 1152 dwords, fully-coalesced dwordx4 / dwordx2
#pragma unroll
    for (int i = 0; i < 4; ++i)
        *(f4v*)(po + 192 + i * 256 + u * 4) = *(const f4v*)(lbuf + i * 256 + u * 4);
    *(f2v*)(po + 192 + 1024 + u * 2) = *(const f2v*)(lbuf + 1024 + u * 2);

    __syncthreads();   // readback done before lbuf is overwritten

    // ---- l3 = 2 outputs: 6 paths -> lbuf[0..1920) == po[1344..3264) ----
    tp_path<0, 2, 2>(wk[9], A0, b2, t5);
#pragma unroll
    for (int m = 0; m < 5; ++m) lbuf[0 * 320 + u * 5 + m] = t5[m];
    tp_path<1, 1, 2>(wk[10], a1, b1, t5);
#pragma unroll
    for (int m = 0; m < 5; ++m) lbuf[1 * 320 + u * 5 + m] = t5[m];
    tp_path<2, 0, 2>(wk[11], a2, B0, t5);
#pragma unroll
    for (int m = 0; m < 5; ++m) lbuf[2 * 320 + u * 5 + m] = t5[m];
    tp_path<2, 2, 2>(wk[12], a2, b2, t5);
#pragma unroll
    for (int m = 0; m < 5; ++m) lbuf[3 * 320 + u * 5 + m] = t5[m];
    tp_path<1, 2, 2>(wk[13], a1, b2, t5);
#pragma unroll
    for (int m = 0; m < 5; ++m) lbuf[4 * 320 + u * 5 + m] = t5[m];
    tp_path<2, 1, 2>(wk[14], a2, b1, t5);
#pragma unroll
    for (int m = 0; m < 5; ++m) lbuf[5 * 320 + u * 5 + m] = t5[m];

    __syncthreads();   // writes visible before readback

    // flush: 1920 dwords, fully-coalesced dwordx4 / dwordx2
#pragma unroll
    for (int i = 0; i < 7; ++i)
        *(f4v*)(po + 1344 + i * 256 + u * 4) = *(const f4v*)(lbuf + i * 256 + u * 4);
    *(f2v*)(po + 1344 + 1792 + u * 2) = *(const f2v*)(lbuf + 1792 + u * 2);
}

extern "C" void kernel_launch(void* const* d_in, const int* in_sizes, int n_in,
                              void* d_out, int out_size, void* d_ws, size_t ws_size,
                              hipStream_t stream) {
    (void)n_in; (void)out_size; (void)d_ws; (void)ws_size;
    const float* x1 = (const float*)d_in[0];
    const float* x2 = (const float*)d_in[1];
    const float* wt = (const float*)d_in[2];
    float* out = (float*)d_out;

    int E = in_sizes[0] / 576;
    long total = (long)E * 64;
    int blocks = (int)((total + 255) / 256);
    dtp_kernel<<<blocks, 256, 0, stream>>>(x1, x2, wt, out, E);
}

// Round 5
// 170.656 us; speedup vs baseline: 1.8559x; 1.1018x over previous
//
#include <hip/hip_runtime.h>

// ============================================================================
// Compile-time real-basis Wigner 3j — mirrors the reference _su2_cg/_q/_w3j
// exactly (double precision at compile time, cast to float for use).
// ============================================================================

__host__ __device__ constexpr double cfact(int n) {
    double r = 1.0;
    for (int i = 2; i <= n; ++i) r *= (double)i;
    return r;
}

__host__ __device__ constexpr double csqrt(double x) {
    if (x <= 0.0) return 0.0;
    double r = x < 1.0 ? 1.0 : x;
    for (int i = 0; i < 80; ++i) r = 0.5 * (r + x / r);
    return r;
}

__host__ __device__ constexpr double su2_cg_elem(int j1, int j2, int j3, int m1, int m2) {
    int m3 = m1 + m2;
    if (m3 < -j3 || m3 > j3) return 0.0;
    double pref = csqrt((double)(2 * j3 + 1) * cfact(j3 + j1 - j2) * cfact(j3 - j1 + j2) *
                        cfact(j1 + j2 - j3) / cfact(j1 + j2 + j3 + 1));
    pref *= csqrt(cfact(j3 + m3) * cfact(j3 - m3) * cfact(j1 - m1) * cfact(j1 + m1) *
                  cfact(j2 - m2) * cfact(j2 + m2));
    double s = 0.0;
    for (int k = 0; k <= j1 + j2 - j3; ++k) {
        int t0 = k, t1 = j1 + j2 - j3 - k, t2 = j1 - m1 - k;
        int t3 = j2 + m2 - k, t4 = j3 - j2 + m1 + k, t5 = j3 - j1 - m2 + k;
        if (t0 < 0 || t1 < 0 || t2 < 0 || t3 < 0 || t4 < 0 || t5 < 0) continue;
        double term = 1.0 / (cfact(t0) * cfact(t1) * cfact(t2) * cfact(t3) * cfact(t4) * cfact(t5));
        s += (k & 1) ? -term : term;
    }
    return pref * s;
}

struct QM { double re[5][5]; double im[5][5]; };

__host__ __device__ constexpr QM qmat(int l) {
    QM q{};
    const double inv2 = 1.0 / csqrt(2.0);
    for (int m = -l; m < 0; ++m) {
        q.re[l + m][l - m] = inv2;
        q.im[l + m][l + m] = -inv2;
    }
    q.re[l][l] = 1.0;
    for (int m = 1; m <= l; ++m) {
        double s = (m & 1) ? -1.0 : 1.0;
        q.re[l + m][l + m] = s * inv2;
        q.im[l + m][l - m] = s * inv2;
    }
    double pr = 1.0, pi = 0.0;
    switch (l & 3) {
        case 1: pr = 0.0; pi = -1.0; break;
        case 2: pr = -1.0; pi = 0.0; break;
        case 3: pr = 0.0; pi = 1.0; break;
        default: break;
    }
    for (int a = 0; a < 5; ++a)
        for (int b = 0; b < 5; ++b) {
            double re = q.re[a][b], im = q.im[a][b];
            q.re[a][b] = re * pr - im * pi;
            q.im[a][b] = re * pi + im * pr;
        }
    return q;
}

struct W3 { double w[5][5][5]; };

__host__ __device__ constexpr W3 make_w3j(int l1, int l2, int l3) {
    W3 o{};
    const int n1 = 2 * l1 + 1, n2 = 2 * l2 + 1, n3 = 2 * l3 + 1;
    double C[5][5]{};
    const double inv = 1.0 / csqrt((double)(2 * l3 + 1));
    for (int i = 0; i < n1; ++i)
        for (int k = 0; k < n2; ++k)
            C[i][k] = su2_cg_elem(l1, l2, l3, i - l1, k - l2) * inv;
    const QM q1 = qmat(l1), q2 = qmat(l2), q3 = qmat(l3);
    for (int j = 0; j < n1; ++j)
        for (int l = 0; l < n2; ++l)
            for (int n = 0; n < n3; ++n) {
                double s = 0.0;
                for (int i = 0; i < n1; ++i)
                    for (int k = 0; k < n2; ++k) {
                        int m = (i - l1) + (k - l2) + l3;
                        if (m < 0 || m >= n3) continue;
                        double cg = C[i][k];
                        if (cg == 0.0) continue;
                        double r1 = q1.re[i][j], i1 = q1.im[i][j];
                        double r2 = q2.re[k][l], i2 = q2.im[k][l];
                        double zr = r1 * r2 - i1 * i2, zi = r1 * i2 + i1 * r2;
                        s += cg * (zr * q3.re[m][n] + zi * q3.im[m][n]);
                    }
                o.w[j][l][n] = s;
            }
    return o;
}

template <int L1, int L2, int L3>
__device__ __forceinline__ void tp_path(float wk, const float* a, const float* b, float* o) {
    constexpr W3 W = make_w3j(L1, L2, L3);
    constexpr double AL = csqrt(2.0 * L3 + 1.0);
#pragma unroll
    for (int n = 0; n < 2 * L3 + 1; ++n) {
        float s = 0.0f;
#pragma unroll
        for (int i = 0; i < 2 * L1 + 1; ++i) {
#pragma unroll
            for (int k = 0; k < 2 * L2 + 1; ++k) {
                const double cw = W.w[i][k][n] * AL;
                if (cw != 0.0) s += (float)cw * (a[i] * b[k]);
            }
        }
        o[n] = wk * s;
    }
}

// may_alias vector types: LDS is written as float and read back as vectors.
typedef float f4b __attribute__((ext_vector_type(4)));
typedef float f2b __attribute__((ext_vector_type(2)));
typedef f4b __attribute__((may_alias)) f4v;
typedef f2b __attribute__((may_alias)) f2v;

// Wave-private LDS staging needs only a compiler memory fence (+ lgkmcnt
// drain): HW DS ops from one wave are in-order; no cross-wave sharing, so no
// s_barrier. __threadfence_block() provides both without barrier bubbles.
__device__ __forceinline__ void lds_fence() { __threadfence_block(); }

// ============================================================================
// Kernel: one thread per (edge, u-channel). wave = one edge, lane = u (0..63).
// Output staging in a 960-float wave-private LDS buffer (15 KiB/block ->
// LDS no longer caps occupancy: 8 blocks/CU = 32 waves/CU). Four phases of
// 3 paths each; every global store instruction is full-line dwordx4/x2.
// ============================================================================

__global__ __launch_bounds__(256) void dtp_kernel(const float* __restrict__ X1,
                                                  const float* __restrict__ X2,
                                                  const float* __restrict__ WT,
                                                  float* __restrict__ OUT, int E) {
    __shared__ __align__(16) float lds[4][960];   // 3840 B/wave, 15 KiB/block

    long idx = (long)blockIdx.x * blockDim.x + threadIdx.x;
    if (idx >= (long)E * 64) return;
    long e = idx >> 6;
    int u = (int)(idx & 63);
    float* lbuf = lds[(threadIdx.x >> 6) & 3];

    const float* p1 = X1 + e * 576;
    const float* p2 = X2 + e * 9;
    const float* pw = WT + e * 960;
    float* po = OUT + e * 3264;

    // ---- x1 loads ----
    float a0 = p1[u];
    float a1[3], a2[5];
#pragma unroll
    for (int m = 0; m < 3; ++m) a1[m] = p1[64 + u * 3 + m];
#pragma unroll
    for (int m = 0; m < 5; ++m) a2[m] = p1[256 + u * 5 + m];

    // ---- x2 loads (tiny, wave-uniform) ----
    float b0 = p2[0];
    float b1[3], b2[5];
#pragma unroll
    for (int m = 0; m < 3; ++m) b1[m] = p2[1 + m];
#pragma unroll
    for (int m = 0; m < 5; ++m) b2[m] = p2[4 + m];

    // ---- weights (coalesced stride-64) ----
    float wk[15];
#pragma unroll
    for (int k = 0; k < 15; ++k) wk[k] = pw[k * 64 + u];

    float A0[1] = {a0}, B0[1] = {b0};
    float t1[1], t3[3], t5[5];

    // ---- l3 = 0 outputs: direct, already full-line coalesced ----
    tp_path<0, 0, 0>(wk[0], A0, B0, t1);  po[0 + u] = t1[0];
    tp_path<1, 1, 0>(wk[1], a1, b1, t1);  po[64 + u] = t1[0];
    tp_path<2, 2, 0>(wk[2], a2, b2, t1);  po[128 + u] = t1[0];

    // ================= phase L1a: paths k3,k4,k5 -> po[192..768) =============
    tp_path<0, 1, 1>(wk[3], A0, b1, t3);
#pragma unroll
    for (int m = 0; m < 3; ++m) lbuf[0 * 192 + u * 3 + m] = t3[m];
    tp_path<1, 0, 1>(wk[4], a1, B0, t3);
#pragma unroll
    for (int m = 0; m < 3; ++m) lbuf[1 * 192 + u * 3 + m] = t3[m];
    tp_path<1, 2, 1>(wk[5], a1, b2, t3);
#pragma unroll
    for (int m = 0; m < 3; ++m) lbuf[2 * 192 + u * 3 + m] = t3[m];

    lds_fence();
#pragma unroll
    for (int i = 0; i < 2; ++i)
        *(f4v*)(po + 192 + i * 256 + u * 4) = *(const f4v*)(lbuf + i * 256 + u * 4);
    po[192 + 512 + u] = lbuf[512 + u];
    lds_fence();

    // ================= phase L1b: paths k6,k7,k8 -> po[768..1344) ============
    tp_path<2, 1, 1>(wk[6], a2, b1, t3);
#pragma unroll
    for (int m = 0; m < 3; ++m) lbuf[0 * 192 + u * 3 + m] = t3[m];
    tp_path<1, 1, 1>(wk[7], a1, b1, t3);
#pragma unroll
    for (int m = 0; m < 3; ++m) lbuf[1 * 192 + u * 3 + m] = t3[m];
    tp_path<2, 2, 1>(wk[8], a2, b2, t3);
#pragma unroll
    for (int m = 0; m < 3; ++m) lbuf[2 * 192 + u * 3 + m] = t3[m];

    lds_fence();
#pragma unroll
    for (int i = 0; i < 2; ++i)
        *(f4v*)(po + 768 + i * 256 + u * 4) = *(const f4v*)(lbuf + i * 256 + u * 4);
    po[768 + 512 + u] = lbuf[512 + u];
    lds_fence();

    // ================= phase L2a: paths k9,k10,k11 -> po[1344..2304) =========
    tp_path<0, 2, 2>(wk[9], A0, b2, t5);
#pragma unroll
    for (int m = 0; m < 5; ++m) lbuf[0 * 320 + u * 5 + m] = t5[m];
    tp_path<1, 1, 2>(wk[10], a1, b1, t5);
#pragma unroll
    for (int m = 0; m < 5; ++m) lbuf[1 * 320 + u * 5 + m] = t5[m];
    tp_path<2, 0, 2>(wk[11], a2, B0, t5);
#pragma unroll
    for (int m = 0; m < 5; ++m) lbuf[2 * 320 + u * 5 + m] = t5[m];

    lds_fence();
#pragma unroll
    for (int i = 0; i < 3; ++i)
        *(f4v*)(po + 1344 + i * 256 + u * 4) = *(const f4v*)(lbuf + i * 256 + u * 4);
    *(f2v*)(po + 1344 + 768 + u * 2) = *(const f2v*)(lbuf + 768 + u * 2);
    po[1344 + 896 + u] = lbuf[896 + u];
    lds_fence();

    // ================= phase L2b: paths k12,k13,k14 -> po[2304..3264) ========
    tp_path<2, 2, 2>(wk[12], a2, b2, t5);
#pragma unroll
    for (int m = 0; m < 5; ++m) lbuf[0 * 320 + u * 5 + m] = t5[m];
    tp_path<1, 2, 2>(wk[13], a1, b2, t5);
#pragma unroll
    for (int m = 0; m < 5; ++m) lbuf[1 * 320 + u * 5 + m] = t5[m];
    tp_path<2, 1, 2>(wk[14], a2, b1, t5);
#pragma unroll
    for (int m = 0; m < 5; ++m) lbuf[2 * 320 + u * 5 + m] = t5[m];

    lds_fence();
#pragma unroll
    for (int i = 0; i < 3; ++i)
        *(f4v*)(po + 2304 + i * 256 + u * 4) = *(const f4v*)(lbuf + i * 256 + u * 4);
    *(f2v*)(po + 2304 + 768 + u * 2) = *(const f2v*)(lbuf + 768 + u * 2);
    po[2304 + 896 + u] = lbuf[896 + u];
}

extern "C" void kernel_launch(void* const* d_in, const int* in_sizes, int n_in,
                              void* d_out, int out_size, void* d_ws, size_t ws_size,
                              hipStream_t stream) {
    (void)n_in; (void)out_size; (void)d_ws; (void)ws_size;
    const float* x1 = (const float*)d_in[0];
    const float* x2 = (const float*)d_in[1];
    const float* wt = (const float*)d_in[2];
    float* out = (float*)d_out;

    int E = in_sizes[0] / 576;
    long total = (long)E * 64;
    int blocks = (int)((total + 255) / 256);
    dtp_kernel<<<blocks, 256, 0, stream>>>(x1, x2, wt, out, E);
}